// Round 1
// baseline (269.213 us; speedup 1.0000x reference)
//
#include <hip/hip_runtime.h>
#include <math.h>

// Problem constants (from reference)
constexpr int B_  = 16;
constexpr int LQ_ = 1024;
constexpr int LK_ = 4096;
constexpr int D_  = 256;
constexpr float HALF_BW_F = 64.0f;         // 128 // 2
constexpr float SCALE = 0.0625f;           // (D^-0.25)^2 = 1/sqrt(256)

constexpr int NB_MAX = 132;                // band width <= 129, padded

__device__ __forceinline__ float wave_reduce_sum(float v) {
    #pragma unroll
    for (int off = 32; off > 0; off >>= 1)
        v += __shfl_xor(v, off, 64);
    return v;
}

__device__ __forceinline__ float wave_reduce_max(float v) {
    #pragma unroll
    for (int off = 32; off > 0; off >>= 1)
        v = fmaxf(v, __shfl_xor(v, off, 64));
    return v;
}

// One block (256 threads = 4 waves) per (b, q) row.
__global__ __launch_bounds__(256) void stripe_attn_kernel(
    const float* __restrict__ Q, const float* __restrict__ K,
    const int* __restrict__ qlen, const int* __restrict__ klen,
    float* __restrict__ Wout)
{
    const int row  = blockIdx.x;           // 0 .. B*LQ-1
    const int b    = row >> 10;            // row / LQ
    const int qi   = row & (LQ_ - 1);
    const int tid  = threadIdx.x;
    const int lane = tid & 63;
    const int wave = tid >> 6;

    __shared__ float s_sc[NB_MAX];
    __shared__ float s_red[4];

    const int   key_len = klen[b];
    const float slope   = (float)key_len / (float)qlen[b];   // fp32 div, matches ref
    const float center  = (float)qi * slope;                 // fp32 mul, matches ref

    // integer band: k >= center-64 && k <= center+64 && k < key_len
    // exact for integer k (all < 2^24)
    int k_lo = (int)ceilf(center - HALF_BW_F);
    if (k_lo < 0) k_lo = 0;
    int k_hi = (int)floorf(center + HALF_BW_F);
    if (k_hi > key_len - 1) k_hi = key_len - 1;
    const int nb = k_hi - k_lo + 1;        // always >= 1 here

    // each lane holds q[b][qi][4*lane .. 4*lane+3]
    const float4 qf = *(const float4*)(Q + ((size_t)b * LQ_ + qi) * D_ + lane * 4);

    // ---- scores: one key per wave per iteration ----
    const float* kbase = K + (size_t)b * LK_ * D_;
    for (int kk = k_lo + wave; kk <= k_hi; kk += 4) {
        const float4 kf = *(const float4*)(kbase + (size_t)kk * D_ + lane * 4);
        float p = qf.x * kf.x + qf.y * kf.y + qf.z * kf.z + qf.w * kf.w;
        p = wave_reduce_sum(p);
        if (lane == 0) s_sc[kk - k_lo] = p * SCALE;
    }
    __syncthreads();

    // ---- softmax over s_sc[0..nb) (nb <= 129 <= 256: one elem/thread) ----
    const float v = (tid < nb) ? s_sc[tid] : -INFINITY;
    float m = wave_reduce_max(v);
    if (lane == 0) s_red[wave] = m;
    __syncthreads();
    m = fmaxf(fmaxf(s_red[0], s_red[1]), fmaxf(s_red[2], s_red[3]));

    const float e = (tid < nb) ? expf(v - m) : 0.0f;
    float s = wave_reduce_sum(e);
    __syncthreads();                       // done reading s_red for max
    if (lane == 0) s_red[wave] = s;
    __syncthreads();
    s = s_red[0] + s_red[1] + s_red[2] + s_red[3];
    const float inv = 1.0f / s;

    if (tid < nb) s_sc[tid] = e * inv;
    __syncthreads();

    // ---- write full 4096-wide row: zeros outside band ----
    float* base = Wout + (size_t)row * LK_;
    #pragma unroll
    for (int j = 0; j < 4; ++j) {
        const int c0 = (tid + j * 256) * 4;    // column of this float4
        float w[4] = {0.0f, 0.0f, 0.0f, 0.0f};
        if (c0 + 3 >= k_lo && c0 <= k_hi) {
            #pragma unroll
            for (int i = 0; i < 4; ++i) {
                const int c = c0 + i;
                if (c >= k_lo && c <= k_hi) w[i] = s_sc[c - k_lo];
            }
        }
        float4 w4;
        w4.x = w[0]; w4.y = w[1]; w4.z = w[2]; w4.w = w[3];
        *(float4*)(base + c0) = w4;
    }
}

extern "C" void kernel_launch(void* const* d_in, const int* in_sizes, int n_in,
                              void* d_out, int out_size, void* d_ws, size_t ws_size,
                              hipStream_t stream) {
    // inputs (setup_inputs order): query, key, value, mask, query_lengths, key_lengths
    const float* Q    = (const float*)d_in[0];
    const float* K    = (const float*)d_in[1];
    const void*  Vsrc = d_in[2];
    const int*   qlen = (const int*)d_in[4];
    const int*   klen = (const int*)d_in[5];

    float* Wout = (float*)d_out;
    const size_t W_ELEMS = (size_t)B_ * LQ_ * LK_;        // 67,108,864
    const size_t V_BYTES = (size_t)B_ * LK_ * D_ * sizeof(float);  // 64 MB

    // output tuple part 2: verbatim copy of value
    hipMemcpyAsync((void*)(Wout + W_ELEMS), Vsrc, V_BYTES,
                   hipMemcpyDeviceToDevice, stream);

    // output tuple part 1: masked softmax weights
    stripe_attn_kernel<<<dim3(B_ * LQ_), dim3(256), 0, stream>>>(
        Q, K, qlen, klen, Wout);
}

// Round 2
// 227.065 us; speedup vs baseline: 1.1856x; 1.1856x over previous
//
#include <hip/hip_runtime.h>
#include <math.h>

// Problem constants (from reference)
constexpr int B_  = 16;
constexpr int LQ_ = 1024;
constexpr int LK_ = 4096;
constexpr int D_  = 256;
constexpr float HALF_BW_F = 64.0f;         // 128 // 2
constexpr float SCALE = 0.0625f;           // (D^-0.25)^2 = 1/sqrt(256)

constexpr int NB_MAX = 132;                // band width <= 129, padded
constexpr int NXCD = 8;
constexpr int ROWS_PER_XCD = (B_ * LQ_) / NXCD;   // 2048

__device__ __forceinline__ float wave_reduce_sum(float v) {
    #pragma unroll
    for (int off = 32; off > 0; off >>= 1)
        v += __shfl_xor(v, off, 64);
    return v;
}

__device__ __forceinline__ float wave_reduce_max(float v) {
    #pragma unroll
    for (int off = 32; off > 0; off >>= 1)
        v = fmaxf(v, __shfl_xor(v, off, 64));
    return v;
}

// One block (256 threads = 4 waves) per (b, q) row. Also copies a 4 KB
// slice of V to the second output.
__global__ __launch_bounds__(256) void stripe_attn_kernel(
    const float* __restrict__ Q, const float* __restrict__ K,
    const float* __restrict__ V,
    const int* __restrict__ qlen, const int* __restrict__ klen,
    float* __restrict__ Wout, float* __restrict__ Vout)
{
    // XCD-aware swizzle: HW dispatches block i to XCD i%8; give each XCD a
    // contiguous 2048-row chunk (= 2 whole batches) so the sliding K-band
    // stays resident in that XCD's private 4 MB L2.
    const int row  = (blockIdx.x & (NXCD - 1)) * ROWS_PER_XCD + (blockIdx.x >> 3);
    const int b    = row >> 10;            // row / LQ
    const int qi   = row & (LQ_ - 1);
    const int tid  = threadIdx.x;
    const int lane = tid & 63;
    const int wave = tid >> 6;

    __shared__ float s_sc[NB_MAX];
    __shared__ float s_red[4];

    // ---- fused V copy: this block's 1024-float slice (one float4/thread)
    {
        const size_t off = (size_t)row * 1024 + (size_t)tid * 4;
        *(float4*)(Vout + off) = *(const float4*)(V + off);
    }

    const int   key_len = klen[b];
    const float slope   = (float)key_len / (float)qlen[b];   // fp32 div, matches ref
    const float center  = (float)qi * slope;                 // fp32 mul, matches ref

    // integer band: k >= center-64 && k <= center+64 && k < key_len
    int k_lo = (int)ceilf(center - HALF_BW_F);
    if (k_lo < 0) k_lo = 0;
    int k_hi = (int)floorf(center + HALF_BW_F);
    if (k_hi > key_len - 1) k_hi = key_len - 1;
    const int nb = k_hi - k_lo + 1;        // always >= 1 here

    // each lane holds q[b][qi][4*lane .. 4*lane+3]
    const float4 qf = *(const float4*)(Q + ((size_t)b * LQ_ + qi) * D_ + lane * 4);

    // ---- scores: one key per wave per iteration ----
    const float* kbase = K + (size_t)b * LK_ * D_;
    for (int kk = k_lo + wave; kk <= k_hi; kk += 4) {
        const float4 kf = *(const float4*)(kbase + (size_t)kk * D_ + lane * 4);
        float p = qf.x * kf.x + qf.y * kf.y + qf.z * kf.z + qf.w * kf.w;
        p = wave_reduce_sum(p);
        if (lane == 0) s_sc[kk - k_lo] = p * SCALE;
    }
    __syncthreads();

    // ---- softmax over s_sc[0..nb) (nb <= 129 <= 256: one elem/thread) ----
    const float v = (tid < nb) ? s_sc[tid] : -INFINITY;
    float m = wave_reduce_max(v);
    if (lane == 0) s_red[wave] = m;
    __syncthreads();
    m = fmaxf(fmaxf(s_red[0], s_red[1]), fmaxf(s_red[2], s_red[3]));

    const float e = (tid < nb) ? expf(v - m) : 0.0f;
    float s = wave_reduce_sum(e);
    __syncthreads();                       // done reading s_red for max
    if (lane == 0) s_red[wave] = s;
    __syncthreads();
    s = s_red[0] + s_red[1] + s_red[2] + s_red[3];
    const float inv = 1.0f / s;

    if (tid < nb) s_sc[tid] = e * inv;
    __syncthreads();

    // ---- write full 4096-wide row: zeros outside band ----
    float* base = Wout + (size_t)row * LK_;
    #pragma unroll
    for (int j = 0; j < 4; ++j) {
        const int c0 = (tid + j * 256) * 4;    // column of this float4
        float w[4] = {0.0f, 0.0f, 0.0f, 0.0f};
        if (c0 + 3 >= k_lo && c0 <= k_hi) {
            #pragma unroll
            for (int i = 0; i < 4; ++i) {
                const int c = c0 + i;
                if (c >= k_lo && c <= k_hi) w[i] = s_sc[c - k_lo];
            }
        }
        float4 w4;
        w4.x = w[0]; w4.y = w[1]; w4.z = w[2]; w4.w = w[3];
        *(float4*)(base + c0) = w4;
    }
}

extern "C" void kernel_launch(void* const* d_in, const int* in_sizes, int n_in,
                              void* d_out, int out_size, void* d_ws, size_t ws_size,
                              hipStream_t stream) {
    // inputs (setup_inputs order): query, key, value, mask, query_lengths, key_lengths
    const float* Q    = (const float*)d_in[0];
    const float* K    = (const float*)d_in[1];
    const float* V    = (const float*)d_in[2];
    const int*   qlen = (const int*)d_in[4];
    const int*   klen = (const int*)d_in[5];

    float* Wout = (float*)d_out;
    const size_t W_ELEMS = (size_t)B_ * LQ_ * LK_;        // 67,108,864
    float* Vout = Wout + W_ELEMS;

    stripe_attn_kernel<<<dim3(B_ * LQ_), dim3(256), 0, stream>>>(
        Q, K, V, qlen, klen, Wout, Vout);
}

// Round 5
// 191.783 us; speedup vs baseline: 1.4037x; 1.1840x over previous
//
#include <hip/hip_runtime.h>
#include <math.h>

// Problem constants (from reference)
constexpr int B_  = 16;
constexpr int LQ_ = 1024;
constexpr int LK_ = 4096;
constexpr int D_  = 256;
constexpr float HALF_BW_F = 64.0f;         // 128 // 2
constexpr float SCALE = 0.0625f;           // (D^-0.25)^2 = 1/sqrt(256)

constexpr int NB_MAX = 132;                // band width <= 129, padded
constexpr int NXCD = 8;
constexpr int ROWS_PER_XCD = (B_ * LQ_) / NXCD;   // 2048

__device__ __forceinline__ float wave_reduce_sum(float v) {
    #pragma unroll
    for (int off = 32; off > 0; off >>= 1)
        v += __shfl_xor(v, off, 64);
    return v;
}

__device__ __forceinline__ float wave_reduce_max(float v) {
    #pragma unroll
    for (int off = 32; off > 0; off >>= 1)
        v = fmaxf(v, __shfl_xor(v, off, 64));
    return v;
}

// DPP row_shr:N — lane i receives from lane i-N (data moves toward HIGHER
// lanes); out-of-range sources read 0 (bound_ctrl=1). After shr4,shr2,shr1
// lane i holds sum(a[i-7..i]); the complete 8-lane-group sum is in the
// group's LAST lane (l==7): lane 7 = a0..a7, lane 15 = a8..a15.
template <int CTRL>
__device__ __forceinline__ float dpp_add(float v) {
    int x = __builtin_amdgcn_update_dpp(0, __float_as_int(v), CTRL, 0xF, 0xF, true);
    return v + __int_as_float(x);
}

// One block (256 threads = 4 waves) per (b, q) row. Also copies a 4 KB
// slice of V to the second output.
__global__ __launch_bounds__(256, 8) void stripe_attn_kernel(
    const float* __restrict__ Q, const float* __restrict__ K,
    const float* __restrict__ V,
    const int* __restrict__ qlen, const int* __restrict__ klen,
    float* __restrict__ Wout, float* __restrict__ Vout)
{
    // XCD-aware swizzle: each XCD owns 2048 consecutive rows so the sliding
    // K-band stays resident in its private 4 MB L2.
    const int row  = (blockIdx.x & (NXCD - 1)) * ROWS_PER_XCD + (blockIdx.x >> 3);
    const int b    = row >> 10;            // row / LQ
    const int qi   = row & (LQ_ - 1);
    const int tid  = threadIdx.x;
    const int lane = tid & 63;
    const int wave = tid >> 6;
    const int g    = lane >> 3;            // key slot 0..7 within wave
    const int l    = lane & 7;             // D-chunk 0..7 (32 floats each)

    __shared__ float s_sc[NB_MAX];
    __shared__ float s_red[4];

    // ---- fused V copy: this block's 1024-float slice (one float4/thread)
    {
        const size_t off = (size_t)row * 1024 + (size_t)tid * 4;
        *(float4*)(Vout + off) = *(const float4*)(V + off);
    }

    const int   key_len = klen[b];
    const float slope   = (float)key_len / (float)qlen[b];   // fp32 div, matches ref
    const float center  = (float)qi * slope;                 // fp32 mul, matches ref

    // integer band: k >= center-64 && k <= center+64 && k < key_len
    int k_lo = (int)ceilf(center - HALF_BW_F);
    if (k_lo < 0) k_lo = 0;
    int k_hi = (int)floorf(center + HALF_BW_F);
    if (k_hi > key_len - 1) k_hi = key_len - 1;
    const int nb = k_hi - k_lo + 1;        // 65..129

    // ---- Q staging: lane l covers dims [j*32 + l*4, +4) for j=0..7 ----
    const float* qrow = Q + ((size_t)b * LQ_ + qi) * D_;
    float4 q[8];
    #pragma unroll
    for (int j = 0; j < 8; ++j)
        q[j] = *(const float4*)(qrow + j * 32 + l * 4);

    // ---- scores: 8 keys per wave per iteration (one key per 8-lane group) --
    const float* kbase = K + (size_t)b * LK_ * D_;
    for (int kk0 = k_lo + wave * 8; kk0 <= k_hi; kk0 += 32) {
        const int key  = kk0 + g;
        const int keyc = (key <= k_hi) ? key : k_hi;   // clamp: safe, in-batch
        const float* kp = kbase + (size_t)keyc * D_ + l * 4;
        float acc = 0.0f;
        #pragma unroll
        for (int j = 0; j < 8; ++j) {
            const float4 kf = *(const float4*)(kp + j * 32);
            acc += q[j].x * kf.x + q[j].y * kf.y + q[j].z * kf.z + q[j].w * kf.w;
        }
        // 8-lane reduce, 3 DPP steps; complete sum lands in lane l==7
        acc = dpp_add<0x114>(acc);   // row_shr:4
        acc = dpp_add<0x112>(acc);   // row_shr:2
        acc = dpp_add<0x111>(acc);   // row_shr:1
        if (l == 7 && key <= k_hi) s_sc[key - k_lo] = acc * SCALE;
    }
    __syncthreads();

    // ---- softmax over s_sc[0..nb) (nb <= 129 <= 256: one elem/thread) ----
    const float v = (tid < nb) ? s_sc[tid] : -INFINITY;
    float m = wave_reduce_max(v);
    if (lane == 0) s_red[wave] = m;
    __syncthreads();
    m = fmaxf(fmaxf(s_red[0], s_red[1]), fmaxf(s_red[2], s_red[3]));

    const float e = (tid < nb) ? expf(v - m) : 0.0f;
    float s = wave_reduce_sum(e);
    __syncthreads();                       // done reading s_red for max
    if (lane == 0) s_red[wave] = s;
    __syncthreads();
    s = s_red[0] + s_red[1] + s_red[2] + s_red[3];
    const float inv = 1.0f / s;

    if (tid < nb) s_sc[tid] = e * inv;
    __syncthreads();

    // ---- write full 4096-wide row: zeros outside band ----
    float* base = Wout + (size_t)row * LK_;
    #pragma unroll
    for (int j = 0; j < 4; ++j) {
        const int c0 = (tid + j * 256) * 4;    // column of this float4
        float w[4] = {0.0f, 0.0f, 0.0f, 0.0f};
        if (c0 + 3 >= k_lo && c0 <= k_hi) {
            #pragma unroll
            for (int i = 0; i < 4; ++i) {
                const int c = c0 + i;
                if (c >= k_lo && c <= k_hi) w[i] = s_sc[c - k_lo];
            }
        }
        float4 w4;
        w4.x = w[0]; w4.y = w[1]; w4.z = w[2]; w4.w = w[3];
        *(float4*)(base + c0) = w4;
    }
}

extern "C" void kernel_launch(void* const* d_in, const int* in_sizes, int n_in,
                              void* d_out, int out_size, void* d_ws, size_t ws_size,
                              hipStream_t stream) {
    // inputs (setup_inputs order): query, key, value, mask, query_lengths, key_lengths
    const float* Q    = (const float*)d_in[0];
    const float* K    = (const float*)d_in[1];
    const float* V    = (const float*)d_in[2];
    const int*   qlen = (const int*)d_in[4];
    const int*   klen = (const int*)d_in[5];

    float* Wout = (float*)d_out;
    const size_t W_ELEMS = (size_t)B_ * LQ_ * LK_;        // 67,108,864
    float* Vout = Wout + W_ELEMS;

    stripe_attn_kernel<<<dim3(B_ * LQ_), dim3(256), 0, stream>>>(
        Q, K, V, qlen, klen, Wout, Vout);
}

// Round 6
// 169.121 us; speedup vs baseline: 1.5918x; 1.1340x over previous
//
#include <hip/hip_runtime.h>
#include <math.h>

// Problem constants (from reference)
constexpr int B_  = 16;
constexpr int LQ_ = 1024;
constexpr int LK_ = 4096;
constexpr int D_  = 256;
constexpr float HALF_BW_F = 64.0f;         // 128 // 2
constexpr float SCALE = 0.0625f;           // (D^-0.25)^2 = 1/sqrt(256)

constexpr int NB_PAD = 192;                // band <=129 + clamp spill (<=135), padded
constexpr int NXCD = 8;
constexpr int NROWBLK = (B_ * LQ_) / 4;    // 4096 blocks, 4 rows (waves) each
constexpr int RB_PER_XCD = NROWBLK / NXCD; // 512

// DPP row_shr:N — lane i receives from lane i-N (toward higher lanes);
// out-of-range sources read 0 (bound_ctrl=1). After shr4,shr2,shr1 the
// complete 8-lane-group sum is in the group's LAST lane (l==7).
template <int CTRL>
__device__ __forceinline__ float dpp_add(float v) {
    int x = __builtin_amdgcn_update_dpp(0, __float_as_int(v), CTRL, 0xF, 0xF, true);
    return v + __int_as_float(x);
}

__device__ __forceinline__ float wave_reduce_sum(float v) {
    #pragma unroll
    for (int off = 32; off > 0; off >>= 1)
        v += __shfl_xor(v, off, 64);
    return v;
}

__device__ __forceinline__ float wave_reduce_max(float v) {
    #pragma unroll
    for (int off = 32; off > 0; off >>= 1)
        v = fmaxf(v, __shfl_xor(v, off, 64));
    return v;
}

// Barrier-free: each WAVE owns one (b,q) row end-to-end. Block = 4 waves =
// 4 consecutive rows; waves never communicate (per-wave LDS regions, and
// LDS ops within a wave are processed in order -> no __syncthreads at all).
__global__ __launch_bounds__(256, 8) void stripe_attn_kernel(
    const float* __restrict__ Q, const float* __restrict__ K,
    const float* __restrict__ V,
    const int* __restrict__ qlen, const int* __restrict__ klen,
    float* __restrict__ Wout, float* __restrict__ Vout)
{
    // XCD-aware swizzle: each XCD owns 512 consecutive row-blocks
    // (= 2048 consecutive rows = 2 batches) -> sliding K-band L2-resident.
    const int rb   = (blockIdx.x & (NXCD - 1)) * RB_PER_XCD + (blockIdx.x >> 3);
    const int tid  = threadIdx.x;
    const int lane = tid & 63;
    const int wave = tid >> 6;
    const int row  = rb * 4 + wave;
    const int b    = row >> 10;            // row / LQ
    const int qi   = row & (LQ_ - 1);
    const int g    = lane >> 3;            // key slot 0..7 within wave
    const int l    = lane & 7;             // D-chunk 0..7 (32 floats each)

    __shared__ float s_sc[4][NB_PAD];      // private region per wave

    // ---- fused V copy: this wave's 1024-float row slice ----
    {
        const float* vs = V    + (size_t)row * 1024;
        float*       vd = Vout + (size_t)row * 1024;
        #pragma unroll
        for (int it = 0; it < 4; ++it) {
            const int o = (it * 64 + lane) * 4;
            *(float4*)(vd + o) = *(const float4*)(vs + o);
        }
    }

    const int   key_len = klen[b];
    const float slope   = (float)key_len / (float)qlen[b];   // fp32 div, matches ref
    const float center  = (float)qi * slope;                 // fp32 mul, matches ref

    // integer band: k >= center-64 && k <= center+64 && k < key_len
    int k_lo = (int)ceilf(center - HALF_BW_F);
    if (k_lo < 0) k_lo = 0;
    int k_hi = (int)floorf(center + HALF_BW_F);
    if (k_hi > key_len - 1) k_hi = key_len - 1;
    const int nb = k_hi - k_lo + 1;        // 65..129

    // ---- Q staging: lane l covers dims [j*32 + l*4, +4) for j=0..7 ----
    const float* qrow = Q + ((size_t)b * LQ_ + qi) * D_;
    float4 q[8];
    #pragma unroll
    for (int j = 0; j < 8; ++j)
        q[j] = *(const float4*)(qrow + j * 32 + l * 4);

    // ---- scores: 8 keys per iteration (one per 8-lane group), ~17 iters ----
    const float* kbase = K + (size_t)b * LK_ * D_;
    float* sw = s_sc[wave];
    for (int kk0 = k_lo; kk0 <= k_hi; kk0 += 8) {
        const int key  = kk0 + g;
        const int keyc = (key <= k_hi) ? key : k_hi;   // clamp: safe, in-batch
        const float* kp = kbase + (size_t)keyc * D_ + l * 4;
        float acc = 0.0f;
        #pragma unroll
        for (int j = 0; j < 8; ++j) {
            const float4 kf = *(const float4*)(kp + j * 32);
            acc += q[j].x * kf.x + q[j].y * kf.y + q[j].z * kf.z + q[j].w * kf.w;
        }
        acc = dpp_add<0x114>(acc);   // row_shr:4
        acc = dpp_add<0x112>(acc);   // row_shr:2
        acc = dpp_add<0x111>(acc);   // row_shr:1
        // clamped keys spill into padding idx in [nb,136) < NB_PAD: harmless
        if (l == 7) sw[key - k_lo] = acc * SCALE;
    }

    // ---- per-wave softmax over sw[0..nb), 3 values per lane ----
    float v0 = sw[lane];
    float v1 = sw[64 + lane];
    float v2 = sw[128 + lane];
    v0 = (lane < nb)       ? v0 : -INFINITY;
    v1 = (64 + lane < nb)  ? v1 : -INFINITY;
    v2 = (128 + lane < nb) ? v2 : -INFINITY;

    const float m  = wave_reduce_max(fmaxf(fmaxf(v0, v1), v2));
    const float e0 = __expf(v0 - m);       // exp(-inf)=0 handles padding
    const float e1 = __expf(v1 - m);
    const float e2 = __expf(v2 - m);
    const float s  = wave_reduce_sum(e0 + e1 + e2);
    const float inv = 1.0f / s;

    sw[lane]       = e0 * inv;             // padding gets 0, never read
    sw[64 + lane]  = e1 * inv;
    sw[128 + lane] = e2 * inv;             // max idx 191 < NB_PAD

    // ---- write full 4096-wide row: zeros outside band ----
    float* base = Wout + (size_t)row * LK_;
    #pragma unroll
    for (int j = 0; j < 16; ++j) {
        const int c0 = (j * 64 + lane) * 4;    // column of this float4
        float w[4] = {0.0f, 0.0f, 0.0f, 0.0f};
        if (c0 + 3 >= k_lo && c0 <= k_hi) {    // coherent skip for ~14/16 stripes
            #pragma unroll
            for (int i = 0; i < 4; ++i) {
                const int c = c0 + i;
                if (c >= k_lo && c <= k_hi) w[i] = sw[c - k_lo];
            }
        }
        float4 w4;
        w4.x = w[0]; w4.y = w[1]; w4.z = w[2]; w4.w = w[3];
        *(float4*)(base + c0) = w4;
    }
}

extern "C" void kernel_launch(void* const* d_in, const int* in_sizes, int n_in,
                              void* d_out, int out_size, void* d_ws, size_t ws_size,
                              hipStream_t stream) {
    // inputs (setup_inputs order): query, key, value, mask, query_lengths, key_lengths
    const float* Q    = (const float*)d_in[0];
    const float* K    = (const float*)d_in[1];
    const float* V    = (const float*)d_in[2];
    const int*   qlen = (const int*)d_in[4];
    const int*   klen = (const int*)d_in[5];

    float* Wout = (float*)d_out;
    const size_t W_ELEMS = (size_t)B_ * LQ_ * LK_;        // 67,108,864
    float* Vout = Wout + W_ELEMS;

    stripe_attn_kernel<<<dim3(NROWBLK), dim3(256), 0, stream>>>(
        Q, K, V, qlen, klen, Wout, Vout);
}

// Round 7
// 154.688 us; speedup vs baseline: 1.7404x; 1.0933x over previous
//
#include <hip/hip_runtime.h>
#include <math.h>

// Problem constants (from reference)
constexpr int B_  = 16;
constexpr int LQ_ = 1024;
constexpr int LK_ = 4096;
constexpr int D_  = 256;
constexpr float HALF_BW_F = 64.0f;         // 128 // 2
constexpr float SCALE = 0.0625f;           // (D^-0.25)^2 = 1/sqrt(256)

constexpr int NB_PAD = 192;                // band <=129 + clamp spill (<=135), padded
constexpr int NXCD = 8;
constexpr int NROWBLK = (B_ * LQ_) / 4;    // 4096 blocks, 4 rows (waves) each
constexpr int RB_PER_XCD = NROWBLK / NXCD; // 512

// DPP row_shr:N — lane i receives from lane i-N (toward higher lanes);
// out-of-range sources read 0 (bound_ctrl=1). After shr4,shr2,shr1 the
// complete 8-lane-group sum is in the group's LAST lane (l==7).
template <int CTRL>
__device__ __forceinline__ float dpp_add(float v) {
    int x = __builtin_amdgcn_update_dpp(0, __float_as_int(v), CTRL, 0xF, 0xF, true);
    return v + __int_as_float(x);
}

__device__ __forceinline__ float wave_reduce_sum(float v) {
    #pragma unroll
    for (int off = 32; off > 0; off >>= 1)
        v += __shfl_xor(v, off, 64);
    return v;
}

__device__ __forceinline__ float wave_reduce_max(float v) {
    #pragma unroll
    for (int off = 32; off > 0; off >>= 1)
        v = fmaxf(v, __shfl_xor(v, off, 64));
    return v;
}

// Barrier-free: each WAVE owns one (b,q) row end-to-end. Block = 4 waves =
// 4 consecutive rows; waves never communicate (per-wave LDS regions; LDS ops
// within a wave are in-order -> no __syncthreads at all).
// __launch_bounds__(256,4): ~128 VGPR budget so Q (32 VGPR) stays resident
// AND up to 16 K-loads stay in flight. (256,8) capped us at 28 VGPR ->
// serialized loads, latency-bound at ~165 us.
__global__ __launch_bounds__(256, 4) void stripe_attn_kernel(
    const float* __restrict__ Q, const float* __restrict__ K,
    const float* __restrict__ V,
    const int* __restrict__ qlen, const int* __restrict__ klen,
    float* __restrict__ Wout, float* __restrict__ Vout)
{
    // XCD-aware swizzle: each XCD owns 512 consecutive row-blocks
    // (= 2048 consecutive rows = 2 batches) -> sliding K-band L2-resident.
    const int rb   = (blockIdx.x & (NXCD - 1)) * RB_PER_XCD + (blockIdx.x >> 3);
    const int tid  = threadIdx.x;
    const int lane = tid & 63;
    const int wave = tid >> 6;
    const int row  = rb * 4 + wave;
    const int b    = row >> 10;            // row / LQ
    const int qi   = row & (LQ_ - 1);
    const int g    = lane >> 3;            // key slot 0..7 within wave
    const int l    = lane & 7;             // D-chunk 0..7 (32 floats each)

    __shared__ float s_sc[4][NB_PAD];      // private region per wave

    // ---- fused V copy: this wave's 1024-float row slice ----
    {
        const float* vs = V    + (size_t)row * 1024;
        float*       vd = Vout + (size_t)row * 1024;
        #pragma unroll
        for (int it = 0; it < 4; ++it) {
            const int o = (it * 64 + lane) * 4;
            *(float4*)(vd + o) = *(const float4*)(vs + o);
        }
    }

    const int   key_len = klen[b];
    const float slope   = (float)key_len / (float)qlen[b];   // fp32 div, matches ref
    const float center  = (float)qi * slope;                 // fp32 mul, matches ref

    // integer band: k >= center-64 && k <= center+64 && k < key_len
    int k_lo = (int)ceilf(center - HALF_BW_F);
    if (k_lo < 0) k_lo = 0;
    int k_hi = (int)floorf(center + HALF_BW_F);
    if (k_hi > key_len - 1) k_hi = key_len - 1;
    const int nb = k_hi - k_lo + 1;        // 65..129

    // ---- Q staging: lane l covers dims [j*32 + l*4, +4) for j=0..7 ----
    const float* qrow = Q + ((size_t)b * LQ_ + qi) * D_;
    float4 q[8];
    #pragma unroll
    for (int j = 0; j < 8; ++j)
        q[j] = *(const float4*)(qrow + j * 32 + l * 4);

    // ---- scores: 8 keys per iteration (one per 8-lane group), ~17 iters ----
    const float* kbase = K + (size_t)b * LK_ * D_;
    float* sw = s_sc[wave];
    #pragma unroll 2
    for (int kk0 = k_lo; kk0 <= k_hi; kk0 += 8) {
        const int key  = kk0 + g;
        const int keyc = (key <= k_hi) ? key : k_hi;   // clamp: safe, in-batch
        const float* kp = kbase + (size_t)keyc * D_ + l * 4;
        float4 kf[8];
        #pragma unroll
        for (int j = 0; j < 8; ++j)
            kf[j] = *(const float4*)(kp + j * 32);     // all 8 loads in flight
        float acc = 0.0f;
        #pragma unroll
        for (int j = 0; j < 8; ++j)
            acc += q[j].x * kf[j].x + q[j].y * kf[j].y +
                   q[j].z * kf[j].z + q[j].w * kf[j].w;
        acc = dpp_add<0x114>(acc);   // row_shr:4
        acc = dpp_add<0x112>(acc);   // row_shr:2
        acc = dpp_add<0x111>(acc);   // row_shr:1
        // clamped keys spill into padding idx in [nb,136) < NB_PAD: harmless
        if (l == 7) sw[key - k_lo] = acc * SCALE;
    }

    // ---- per-wave softmax over sw[0..nb), 3 values per lane ----
    float v0 = sw[lane];
    float v1 = sw[64 + lane];
    float v2 = sw[128 + lane];
    v0 = (lane < nb)       ? v0 : -INFINITY;
    v1 = (64 + lane < nb)  ? v1 : -INFINITY;
    v2 = (128 + lane < nb) ? v2 : -INFINITY;

    const float m  = wave_reduce_max(fmaxf(fmaxf(v0, v1), v2));
    const float e0 = __expf(v0 - m);       // exp(-inf)=0 handles padding
    const float e1 = __expf(v1 - m);
    const float e2 = __expf(v2 - m);
    const float s  = wave_reduce_sum(e0 + e1 + e2);
    const float inv = 1.0f / s;

    sw[lane]       = e0 * inv;             // padding gets 0, never read
    sw[64 + lane]  = e1 * inv;
    sw[128 + lane] = e2 * inv;             // max idx 191 < NB_PAD

    // ---- write full 4096-wide row: zeros outside band ----
    float* base = Wout + (size_t)row * LK_;
    #pragma unroll
    for (int j = 0; j < 16; ++j) {
        const int c0 = (j * 64 + lane) * 4;    // column of this float4
        float w[4] = {0.0f, 0.0f, 0.0f, 0.0f};
        if (c0 + 3 >= k_lo && c0 <= k_hi) {    // coherent skip for ~14/16 stripes
            #pragma unroll
            for (int i = 0; i < 4; ++i) {
                const int c = c0 + i;
                if (c >= k_lo && c <= k_hi) w[i] = sw[c - k_lo];
            }
        }
        float4 w4;
        w4.x = w[0]; w4.y = w[1]; w4.z = w[2]; w4.w = w[3];
        *(float4*)(base + c0) = w4;
    }
}

extern "C" void kernel_launch(void* const* d_in, const int* in_sizes, int n_in,
                              void* d_out, int out_size, void* d_ws, size_t ws_size,
                              hipStream_t stream) {
    // inputs (setup_inputs order): query, key, value, mask, query_lengths, key_lengths
    const float* Q    = (const float*)d_in[0];
    const float* K    = (const float*)d_in[1];
    const float* V    = (const float*)d_in[2];
    const int*   qlen = (const int*)d_in[4];
    const int*   klen = (const int*)d_in[5];

    float* Wout = (float*)d_out;
    const size_t W_ELEMS = (size_t)B_ * LQ_ * LK_;        // 67,108,864
    float* Vout = Wout + W_ELEMS;

    stripe_attn_kernel<<<dim3(NROWBLK), dim3(256), 0, stream>>>(
        Q, K, V, qlen, klen, Wout, Vout);
}

// Round 9
// 120.748 us; speedup vs baseline: 2.2295x; 1.2811x over previous
//
#include <hip/hip_runtime.h>
#include <math.h>

// Problem constants (from reference)
constexpr int B_  = 16;
constexpr int LQ_ = 1024;
constexpr int LK_ = 4096;
constexpr int D_  = 256;
constexpr float HALF_BW_F = 64.0f;         // 128 // 2
constexpr float SCALE = 0.0625f;           // (D^-0.25)^2 = 1/sqrt(256)

// native clang vector for nontemporal builtins (HIP_vector_type is rejected)
typedef float fx4 __attribute__((ext_vector_type(4)));

// union band of 4 consecutive rows <= 129 + 3*slope(<=4) = 141; softmax
// covers 9*16 = 144 slots; pad to 168 (168 % 32 == 8 -> the 4 per-row
// arrays start on different banks)
constexpr int NB_PAD = 168;
constexpr int ROWS_PER_BLK = 16;                 // 4 waves x 4 rows
constexpr int NBLK = (B_ * LQ_) / ROWS_PER_BLK; // 1024
constexpr int NXCD = 8;
constexpr int BLK_PER_XCD = NBLK / NXCD;        // 128

// DPP row_shr:N — lane i receives from lane i-N (toward higher lanes) within
// the 16-lane DPP row; out-of-range sources read 0 (bound_ctrl=1). After
// shr8,shr4,shr2,shr1 the complete 16-lane sum is in the row's last lane
// (l==15).
template <int CTRL>
__device__ __forceinline__ float dpp_add(float v) {
    int x = __builtin_amdgcn_update_dpp(0, __float_as_int(v), CTRL, 0xF, 0xF, true);
    return v + __int_as_float(x);
}

// reductions within a 16-lane group (xor offsets stay inside the group)
__device__ __forceinline__ float grp16_max(float v) {
    #pragma unroll
    for (int off = 8; off > 0; off >>= 1)
        v = fmaxf(v, __shfl_xor(v, off, 64));
    return v;
}
__device__ __forceinline__ float grp16_sum(float v) {
    #pragma unroll
    for (int off = 8; off > 0; off >>= 1)
        v += __shfl_xor(v, off, 64);
    return v;
}

// Barrier-free: each WAVE owns FOUR consecutive (b,q) rows end-to-end —
// one K-band load serves 4 rows (bands overlap >=125/129 keys). Block =
// 4 waves = 16 consecutive rows, all in one batch; waves never communicate.
__global__ __launch_bounds__(256, 4) void stripe_attn_kernel(
    const float* __restrict__ Q, const float* __restrict__ K,
    const float* __restrict__ V,
    const int* __restrict__ qlen, const int* __restrict__ klen,
    float* __restrict__ Wout, float* __restrict__ Vout)
{
    // XCD-aware swizzle: each XCD owns 128 consecutive blocks (2048 rows =
    // 2 batches) -> sliding K-band stays in its private 4 MB L2.
    const int rb   = (blockIdx.x & (NXCD - 1)) * BLK_PER_XCD + (blockIdx.x >> 3);
    const int tid  = threadIdx.x;
    const int lane = tid & 63;
    const int wave = tid >> 6;
    const int g    = lane >> 4;            // key slot 0..3 within wave
    const int l    = lane & 15;            // D-chunk 0..15 (16 floats each)
    const int row0 = rb * ROWS_PER_BLK + wave * 4;   // first of 4 rows
    const int b    = row0 >> 10;           // same batch for all 16 block rows
    const int qi0  = row0 & (LQ_ - 1);

    __shared__ float s_sc[4][4 * NB_PAD];  // [wave][row*NB_PAD + slot]

    // ---- fused flat V copy: this wave's 4096-float slice (streaming) ----
    {
        const float* vs = V    + (size_t)row0 * 1024;
        float*       vd = Vout + (size_t)row0 * 1024;
        #pragma unroll
        for (int it = 0; it < 16; ++it) {
            const int o = (it * 64 + lane) * 4;
            fx4 t = __builtin_nontemporal_load((const fx4*)(vs + o));
            __builtin_nontemporal_store(t, (fx4*)(vd + o));
        }
    }

    const int   key_len = klen[b];
    const float slope   = (float)key_len / (float)qlen[b];   // fp32 div (ref)

    // per-row integer band (exact fp32 arithmetic as reference)
    int k_lo[4], k_hi[4];                  // only static-indexed below
    #pragma unroll
    for (int r = 0; r < 4; ++r) {
        const float center = (float)(qi0 + r) * slope;
        int lo = (int)ceilf(center - HALF_BW_F); if (lo < 0) lo = 0;
        int hi = (int)floorf(center + HALF_BW_F); if (hi > key_len - 1) hi = key_len - 1;
        k_lo[r] = lo; k_hi[r] = hi;
    }
    const int lo0 = k_lo[0], hi3 = k_hi[3];    // union band (nondecreasing)

    // ---- Q staging: 4 rows x 4 float4 (lane l covers floats l*16..l*16+15)
    const float* qbase = Q + ((size_t)b * LQ_ + qi0) * D_;
    float4 q0[4], q1[4], q2[4], q3[4];
    #pragma unroll
    for (int m = 0; m < 4; ++m) {
        q0[m] = *(const float4*)(qbase + 0 * D_ + l * 16 + m * 4);
        q1[m] = *(const float4*)(qbase + 1 * D_ + l * 16 + m * 4);
        q2[m] = *(const float4*)(qbase + 2 * D_ + l * 16 + m * 4);
        q3[m] = *(const float4*)(qbase + 3 * D_ + l * 16 + m * 4);
    }

    // ---- scores: 4 keys/iter (one per 16-lane group), each serves 4 rows --
    const float* kbase = K + (size_t)b * LK_ * D_;
    float* sw = s_sc[wave];
    for (int kk0 = lo0; kk0 <= hi3; kk0 += 4) {
        const int key  = kk0 + g;
        const int keyc = (key <= hi3) ? key : hi3;   // clamp: safe, in-batch
        const float* kp = kbase + (size_t)keyc * D_ + l * 16;
        float4 kf[4];
        #pragma unroll
        for (int m = 0; m < 4; ++m)
            kf[m] = *(const float4*)(kp + m * 4);    // 4 loads in flight
        float a0 = 0.f, a1 = 0.f, a2 = 0.f, a3 = 0.f;
        #pragma unroll
        for (int m = 0; m < 4; ++m) {
            a0 += q0[m].x*kf[m].x + q0[m].y*kf[m].y + q0[m].z*kf[m].z + q0[m].w*kf[m].w;
            a1 += q1[m].x*kf[m].x + q1[m].y*kf[m].y + q1[m].z*kf[m].z + q1[m].w*kf[m].w;
            a2 += q2[m].x*kf[m].x + q2[m].y*kf[m].y + q2[m].z*kf[m].z + q2[m].w*kf[m].w;
            a3 += q3[m].x*kf[m].x + q3[m].y*kf[m].y + q3[m].z*kf[m].z + q3[m].w*kf[m].w;
        }
        // 16-lane reduce per row-acc; complete sums land in l==15
        a0 = dpp_add<0x118>(a0); a0 = dpp_add<0x114>(a0);
        a0 = dpp_add<0x112>(a0); a0 = dpp_add<0x111>(a0);
        a1 = dpp_add<0x118>(a1); a1 = dpp_add<0x114>(a1);
        a1 = dpp_add<0x112>(a1); a1 = dpp_add<0x111>(a1);
        a2 = dpp_add<0x118>(a2); a2 = dpp_add<0x114>(a2);
        a2 = dpp_add<0x112>(a2); a2 = dpp_add<0x111>(a2);
        a3 = dpp_add<0x118>(a3); a3 = dpp_add<0x114>(a3);
        a3 = dpp_add<0x112>(a3); a3 = dpp_add<0x111>(a3);
        if (l == 15) {   // key unclamped in conditions -> clamped dup never stores
            if (key >= k_lo[0] && key <= k_hi[0]) sw[0*NB_PAD + key - k_lo[0]] = a0 * SCALE;
            if (key >= k_lo[1] && key <= k_hi[1]) sw[1*NB_PAD + key - k_lo[1]] = a1 * SCALE;
            if (key >= k_lo[2] && key <= k_hi[2]) sw[2*NB_PAD + key - k_lo[2]] = a2 * SCALE;
            if (key >= k_lo[3] && key <= k_hi[3]) sw[3*NB_PAD + key - k_lo[3]] = a3 * SCALE;
        }
    }

    // ---- softmax: 16-lane group g owns row g (9 values per lane) ----
    // recompute band from scalars (k_lo[g] with runtime g would spill, rule #20)
    const float center_g = (float)(qi0 + g) * slope;
    int klo_g = (int)ceilf(center_g - HALF_BW_F); if (klo_g < 0) klo_g = 0;
    int khi_g = (int)floorf(center_g + HALF_BW_F); if (khi_g > key_len - 1) khi_g = key_len - 1;
    const int nb_g = khi_g - klo_g + 1;    // 65..129
    float* sg = sw + g * NB_PAD;

    float vj[9];
    #pragma unroll
    for (int j = 0; j < 9; ++j) {
        const int idx = l + j * 16;
        vj[j] = (idx < nb_g) ? sg[idx] : -INFINITY;
    }
    float mx = vj[0];
    #pragma unroll
    for (int j = 1; j < 9; ++j) mx = fmaxf(mx, vj[j]);
    mx = grp16_max(mx);

    float ej[9], ssum = 0.f;
    #pragma unroll
    for (int j = 0; j < 9; ++j) { ej[j] = __expf(vj[j] - mx); ssum += ej[j]; }
    ssum = grp16_sum(ssum);
    const float inv = 1.0f / ssum;
    #pragma unroll
    for (int j = 0; j < 9; ++j)
        sg[l + j * 16] = ej[j] * inv;      // padding slots get 0, never read

    // ---- write 4 full 4096-wide rows: zeros outside band (streaming) ----
    #pragma unroll
    for (int r = 0; r < 4; ++r) {
        const int klo = k_lo[r], khi = k_hi[r];
        float* base = Wout + (size_t)(row0 + r) * LK_;
        const float* sr = sw + r * NB_PAD;
        #pragma unroll
        for (int j = 0; j < 16; ++j) {
            const int c0 = (j * 64 + lane) * 4;        // column of this float4
            float w[4] = {0.f, 0.f, 0.f, 0.f};
            if (c0 + 3 >= klo && c0 <= khi) {          // coherent skip ~14/16
                #pragma unroll
                for (int i = 0; i < 4; ++i) {
                    const int c = c0 + i;
                    if (c >= klo && c <= khi) w[i] = sr[c - klo];
                }
            }
            fx4 w4; w4.x = w[0]; w4.y = w[1]; w4.z = w[2]; w4.w = w[3];
            __builtin_nontemporal_store(w4, (fx4*)(base + c0));
        }
    }
}

extern "C" void kernel_launch(void* const* d_in, const int* in_sizes, int n_in,
                              void* d_out, int out_size, void* d_ws, size_t ws_size,
                              hipStream_t stream) {
    // inputs (setup_inputs order): query, key, value, mask, query_lengths, key_lengths
    const float* Q    = (const float*)d_in[0];
    const float* K    = (const float*)d_in[1];
    const float* V    = (const float*)d_in[2];
    const int*   qlen = (const int*)d_in[4];
    const int*   klen = (const int*)d_in[5];

    float* Wout = (float*)d_out;
    const size_t W_ELEMS = (size_t)B_ * LQ_ * LK_;        // 67,108,864
    float* Vout = Wout + W_ELEMS;

    stripe_attn_kernel<<<dim3(NBLK), dim3(256), 0, stream>>>(
        Q, K, V, qlen, klen, Wout, Vout);
}

// Round 10
// 114.731 us; speedup vs baseline: 2.3465x; 1.0524x over previous
//
#include <hip/hip_runtime.h>
#include <math.h>

// Problem constants (from reference)
constexpr int B_  = 16;
constexpr int LQ_ = 1024;
constexpr int LK_ = 4096;
constexpr int D_  = 256;
constexpr float HALF_BW_F = 64.0f;         // 128 // 2
constexpr float SCALE = 0.0625f;           // (D^-0.25)^2 = 1/sqrt(256)

// native clang vector for nontemporal builtins (HIP_vector_type is rejected)
typedef float fx4 __attribute__((ext_vector_type(4)));

// union band of 4 consecutive rows <= 129 + 3*slope(<=4) = 141; softmax
// covers 9*16 = 144 slots; pad to 168 (168 % 32 == 8 -> the 4 per-row
// arrays start on different banks)
constexpr int NB_PAD = 168;
constexpr int ROWS_PER_BLK = 16;                 // 4 waves x 4 rows
constexpr int NBLK = (B_ * LQ_) / ROWS_PER_BLK; // 1024
constexpr int NXCD = 8;
constexpr int BLK_PER_XCD = NBLK / NXCD;        // 128

// DPP row_shr:N — lane i receives from lane i-N (toward higher lanes) within
// the 16-lane DPP row; out-of-range sources read 0 (bound_ctrl=1). After
// shr8,shr4,shr2,shr1 the complete 16-lane sum is in the row's last lane
// (l==15).
template <int CTRL>
__device__ __forceinline__ float dpp_add(float v) {
    int x = __builtin_amdgcn_update_dpp(0, __float_as_int(v), CTRL, 0xF, 0xF, true);
    return v + __int_as_float(x);
}

// reductions within a 16-lane group (xor offsets stay inside the group)
__device__ __forceinline__ float grp16_max(float v) {
    #pragma unroll
    for (int off = 8; off > 0; off >>= 1)
        v = fmaxf(v, __shfl_xor(v, off, 64));
    return v;
}
__device__ __forceinline__ float grp16_sum(float v) {
    #pragma unroll
    for (int off = 8; off > 0; off >>= 1)
        v += __shfl_xor(v, off, 64);
    return v;
}

// Barrier-free: each WAVE owns FOUR consecutive (b,q) rows end-to-end.
// Phase order is chosen to overlap HBM stores with compute: all zero
// stripes of W (~14-15/16 of each row, no data dependency) and the V copy
// are issued BEFORE the score loop; only the <=2 band stripes per row are
// stored after softmax. Stores drain while loads/FMAs execute.
__global__ __launch_bounds__(256, 4) void stripe_attn_kernel(
    const float* __restrict__ Q, const float* __restrict__ K,
    const float* __restrict__ V,
    const int* __restrict__ qlen, const int* __restrict__ klen,
    float* __restrict__ Wout, float* __restrict__ Vout)
{
    // XCD-aware swizzle: each XCD owns 128 consecutive blocks (2048 rows =
    // 2 batches) -> sliding K-band stays in its private 4 MB L2.
    const int rb   = (blockIdx.x & (NXCD - 1)) * BLK_PER_XCD + (blockIdx.x >> 3);
    const int tid  = threadIdx.x;
    const int lane = tid & 63;
    const int wave = tid >> 6;
    const int g    = lane >> 4;            // key slot 0..3 within wave
    const int l    = lane & 15;            // D-chunk 0..15 (16 floats each)
    const int row0 = rb * ROWS_PER_BLK + wave * 4;   // first of 4 rows
    const int b    = row0 >> 10;           // same batch for all 16 block rows
    const int qi0  = row0 & (LQ_ - 1);

    __shared__ float s_sc[4][4 * NB_PAD];  // [wave][row*NB_PAD + slot]

    const int   key_len = klen[b];
    const float slope   = (float)key_len / (float)qlen[b];   // fp32 div (ref)

    // per-row integer band (exact fp32 arithmetic as reference)
    int k_lo[4], k_hi[4];                  // only static-indexed below
    #pragma unroll
    for (int r = 0; r < 4; ++r) {
        const float center = (float)(qi0 + r) * slope;
        int lo = (int)ceilf(center - HALF_BW_F); if (lo < 0) lo = 0;
        int hi = (int)floorf(center + HALF_BW_F); if (hi > key_len - 1) hi = key_len - 1;
        k_lo[r] = lo; k_hi[r] = hi;
    }
    const int lo0 = k_lo[0], hi3 = k_hi[3];    // union band (nondecreasing)

    // ---- EARLY: zero stripes of W (no data dependency; fire-and-forget) ----
    // Each row = 16 stripes of 256 floats; the 129-wide band touches at most
    // 2 stripes [klo>>8, khi>>8]. Conditions are wave-uniform (cheap).
    {
        const fx4 z4 = {0.f, 0.f, 0.f, 0.f};
        #pragma unroll
        for (int r = 0; r < 4; ++r) {
            const int s_lo = k_lo[r] >> 8, s_hi = k_hi[r] >> 8;
            float* base = Wout + (size_t)(row0 + r) * LK_;
            #pragma unroll
            for (int j = 0; j < 16; ++j) {
                if (j < s_lo || j > s_hi)
                    __builtin_nontemporal_store(z4, (fx4*)(base + (j * 64 + lane) * 4));
            }
        }
    }

    // ---- EARLY: fused V copy (independent of everything) ----
    {
        const float* vs = V    + (size_t)row0 * 1024;
        float*       vd = Vout + (size_t)row0 * 1024;
        #pragma unroll
        for (int it = 0; it < 16; ++it) {
            const int o = (it * 64 + lane) * 4;
            fx4 t = __builtin_nontemporal_load((const fx4*)(vs + o));
            __builtin_nontemporal_store(t, (fx4*)(vd + o));
        }
    }

    // ---- Q staging: 4 rows x 4 float4 (lane l covers floats l*16..l*16+15)
    const float* qbase = Q + ((size_t)b * LQ_ + qi0) * D_;
    float4 q0[4], q1[4], q2[4], q3[4];
    #pragma unroll
    for (int m = 0; m < 4; ++m) {
        q0[m] = *(const float4*)(qbase + 0 * D_ + l * 16 + m * 4);
        q1[m] = *(const float4*)(qbase + 1 * D_ + l * 16 + m * 4);
        q2[m] = *(const float4*)(qbase + 2 * D_ + l * 16 + m * 4);
        q3[m] = *(const float4*)(qbase + 3 * D_ + l * 16 + m * 4);
    }

    // ---- scores: 4 keys/iter (one per 16-lane group), each serves 4 rows --
    const float* kbase = K + (size_t)b * LK_ * D_;
    float* sw = s_sc[wave];
    for (int kk0 = lo0; kk0 <= hi3; kk0 += 4) {
        const int key  = kk0 + g;
        const int keyc = (key <= hi3) ? key : hi3;   // clamp: safe, in-batch
        const float* kp = kbase + (size_t)keyc * D_ + l * 16;
        float4 kf[4];
        #pragma unroll
        for (int m = 0; m < 4; ++m)
            kf[m] = *(const float4*)(kp + m * 4);    // 4 loads in flight
        float a0 = 0.f, a1 = 0.f, a2 = 0.f, a3 = 0.f;
        #pragma unroll
        for (int m = 0; m < 4; ++m) {
            a0 += q0[m].x*kf[m].x + q0[m].y*kf[m].y + q0[m].z*kf[m].z + q0[m].w*kf[m].w;
            a1 += q1[m].x*kf[m].x + q1[m].y*kf[m].y + q1[m].z*kf[m].z + q1[m].w*kf[m].w;
            a2 += q2[m].x*kf[m].x + q2[m].y*kf[m].y + q2[m].z*kf[m].z + q2[m].w*kf[m].w;
            a3 += q3[m].x*kf[m].x + q3[m].y*kf[m].y + q3[m].z*kf[m].z + q3[m].w*kf[m].w;
        }
        // 16-lane reduce per row-acc; complete sums land in l==15
        a0 = dpp_add<0x118>(a0); a0 = dpp_add<0x114>(a0);
        a0 = dpp_add<0x112>(a0); a0 = dpp_add<0x111>(a0);
        a1 = dpp_add<0x118>(a1); a1 = dpp_add<0x114>(a1);
        a1 = dpp_add<0x112>(a1); a1 = dpp_add<0x111>(a1);
        a2 = dpp_add<0x118>(a2); a2 = dpp_add<0x114>(a2);
        a2 = dpp_add<0x112>(a2); a2 = dpp_add<0x111>(a2);
        a3 = dpp_add<0x118>(a3); a3 = dpp_add<0x114>(a3);
        a3 = dpp_add<0x112>(a3); a3 = dpp_add<0x111>(a3);
        if (l == 15) {   // key unclamped in conditions -> clamped dup never stores
            if (key >= k_lo[0] && key <= k_hi[0]) sw[0*NB_PAD + key - k_lo[0]] = a0 * SCALE;
            if (key >= k_lo[1] && key <= k_hi[1]) sw[1*NB_PAD + key - k_lo[1]] = a1 * SCALE;
            if (key >= k_lo[2] && key <= k_hi[2]) sw[2*NB_PAD + key - k_lo[2]] = a2 * SCALE;
            if (key >= k_lo[3] && key <= k_hi[3]) sw[3*NB_PAD + key - k_lo[3]] = a3 * SCALE;
        }
    }

    // ---- softmax: 16-lane group g owns row g (9 values per lane) ----
    // recompute band from scalars (k_lo[g] with runtime g would spill, rule #20)
    const float center_g = (float)(qi0 + g) * slope;
    int klo_g = (int)ceilf(center_g - HALF_BW_F); if (klo_g < 0) klo_g = 0;
    int khi_g = (int)floorf(center_g + HALF_BW_F); if (khi_g > key_len - 1) khi_g = key_len - 1;
    const int nb_g = khi_g - klo_g + 1;    // 65..129
    float* sg = sw + g * NB_PAD;

    float vj[9];
    #pragma unroll
    for (int j = 0; j < 9; ++j) {
        const int idx = l + j * 16;
        vj[j] = (idx < nb_g) ? sg[idx] : -INFINITY;
    }
    float mx = vj[0];
    #pragma unroll
    for (int j = 1; j < 9; ++j) mx = fmaxf(mx, vj[j]);
    mx = grp16_max(mx);

    float ej[9], ssum = 0.f;
    #pragma unroll
    for (int j = 0; j < 9; ++j) { ej[j] = __expf(vj[j] - mx); ssum += ej[j]; }
    ssum = grp16_sum(ssum);
    const float inv = 1.0f / ssum;
    #pragma unroll
    for (int j = 0; j < 9; ++j)
        sg[l + j * 16] = ej[j] * inv;      // padding slots get 0, never read

    // ---- DEFERRED: band stripes only (<=2 per row) ----
    #pragma unroll
    for (int r = 0; r < 4; ++r) {
        const int klo = k_lo[r], khi = k_hi[r];
        const int s_lo = klo >> 8, s_hi = khi >> 8;
        float* base = Wout + (size_t)(row0 + r) * LK_;
        const float* sr = sw + r * NB_PAD;
        for (int j = s_lo; j <= s_hi; ++j) {           // <=2 iterations
            const int c0 = (j * 64 + lane) * 4;        // column of this float4
            float w[4] = {0.f, 0.f, 0.f, 0.f};
            if (c0 + 3 >= klo && c0 <= khi) {
                #pragma unroll
                for (int i = 0; i < 4; ++i) {
                    const int c = c0 + i;
                    if (c >= klo && c <= khi) w[i] = sr[c - klo];
                }
            }
            fx4 w4; w4.x = w[0]; w4.y = w[1]; w4.z = w[2]; w4.w = w[3];
            __builtin_nontemporal_store(w4, (fx4*)(base + c0));
        }
    }
}

extern "C" void kernel_launch(void* const* d_in, const int* in_sizes, int n_in,
                              void* d_out, int out_size, void* d_ws, size_t ws_size,
                              hipStream_t stream) {
    // inputs (setup_inputs order): query, key, value, mask, query_lengths, key_lengths
    const float* Q    = (const float*)d_in[0];
    const float* K    = (const float*)d_in[1];
    const float* V    = (const float*)d_in[2];
    const int*   qlen = (const int*)d_in[4];
    const int*   klen = (const int*)d_in[5];

    float* Wout = (float*)d_out;
    const size_t W_ELEMS = (size_t)B_ * LQ_ * LK_;        // 67,108,864
    float* Vout = Wout + W_ELEMS;

    stripe_attn_kernel<<<dim3(NBLK), dim3(256), 0, stream>>>(
        Q, K, V, qlen, klen, Wout, Vout);
}